// Round 5
// baseline (1097.352 us; speedup 1.0000x reference)
//
#include <hip/hip_runtime.h>
#include <hip/hip_bf16.h>
#include <cmath>

#define T_TOK 8192
#define HID 1024
#define INTER_D 2816
#define NEXP 8
#define NSLOT (T_TOK * 2)

typedef __bf16 bf16x8 __attribute__((ext_vector_type(8)));
typedef __bf16 bf16x4 __attribute__((ext_vector_type(4)));
typedef float f32x4 __attribute__((ext_vector_type(4)));
typedef float f32x16 __attribute__((ext_vector_type(16)));

#define MFMA32(a, b, c) __builtin_amdgcn_mfma_f32_32x32x16_bf16(a, b, c, 0, 0, 0)

// ---- workspace layout (bytes) ----
#define XB_OFF    ((size_t)0)                       // bf16 x [T][H]           16.8 MB
#define WGT_OFF   ((size_t)16777216)                // bf16 wgT [E][I][H]      46.1 MB
#define WUT_OFF   ((size_t)62914560)                // bf16 wuT [E][I][H]      46.1 MB
#define WDT_OFF   ((size_t)109051904)               // bf16 wdT [E][H][I]      46.1 MB
#define INTER_OFF ((size_t)155189248)               // bf16 inter [S][I]       92.3 MB
#define ST_OFF    ((size_t)247463936)               // int slot_token[S]
#define SW_OFF    ((size_t)247529472)               // float slot_w[S]
#define TI_OFF    ((size_t)247595008)               // int topk_idx[T][2]
#define TW_OFF    ((size_t)247660544)               // float topk_w[T][2]
#define CTRL_OFF  ((size_t)247726080)               // counts@0, offs@64
#define WS_NEED   ((size_t)247726336)

__device__ __forceinline__ void async16(const void* g, void* l) {
  __builtin_amdgcn_global_load_lds(
      (const __attribute__((address_space(1))) unsigned int*)g,
      (__attribute__((address_space(3))) unsigned int*)l, 16, 0, 0);
}

// ---------------- router: logits (fp64 accum), top-2, renorm weights --------
// Also converts x -> bf16 xb on the fly (router already reads all of x).
__global__ void router_k(const float* __restrict__ x, const float* __restrict__ rw,
                         __bf16* __restrict__ xb,
                         int* __restrict__ topk_idx, float* __restrict__ topk_w,
                         int* __restrict__ counts) {
  int t = blockIdx.x;
  int lane = threadIdx.x;
  double acc[NEXP];
#pragma unroll
  for (int e = 0; e < NEXP; e++) acc[e] = 0.0;
  const float* xr = x + (size_t)t * HID;
  __bf16* xbr = xb + (size_t)t * HID;
  for (int kk = 0; kk < HID / 64; kk++) {
    int k = kk * 64 + lane;
    float xf = xr[k];
    xbr[k] = (__bf16)xf;
    double xv = (double)xf;
#pragma unroll
    for (int e = 0; e < NEXP; e++) acc[e] += xv * (double)rw[k * NEXP + e];
  }
#pragma unroll
  for (int off = 32; off >= 1; off >>= 1)
#pragma unroll
    for (int e = 0; e < NEXP; e++) acc[e] += __shfl_xor(acc[e], off);
  if (lane == 0) {
    int i0 = 0;
    double v0 = acc[0];
    for (int e = 1; e < NEXP; e++)
      if (acc[e] > v0) { v0 = acc[e]; i0 = e; }
    int i1 = -1;
    double v1 = -1e300;
    for (int e = 0; e < NEXP; e++)
      if (e != i0 && acc[e] > v1) { v1 = acc[e]; i1 = e; }
    double w0 = 1.0 / (1.0 + exp(v1 - v0));
    topk_idx[2 * t] = i0;
    topk_idx[2 * t + 1] = i1;
    topk_w[2 * t] = (float)w0;
    topk_w[2 * t + 1] = (float)(1.0 - w0);
    atomicAdd(&counts[i0], 1);
    atomicAdd(&counts[i1], 1);
  }
}

// ---- single-block scatter, wave-aggregated ranks -> slot_token / slot_w ----
__global__ void scatter_k(const int* __restrict__ topk_idx, const float* __restrict__ topk_w,
                          const int* __restrict__ counts, int* __restrict__ offs,
                          int* __restrict__ slot_token, float* __restrict__ slot_w) {
  __shared__ int scur[NEXP];
  int t = threadIdx.x;  // 256
  if (t == 0) {
    int s = 0;
    for (int e = 0; e < NEXP; e++) {
      offs[e] = s;
      scur[e] = s;
      s += counts[e];
    }
  }
  __syncthreads();
  int lane = t & 63;
  unsigned long long ltmask = (1ull << lane) - 1ull;
  for (int i = t; i < NSLOT; i += 256) {  // NSLOT % 256 == 0: every wave full
    int e = topk_idx[i];
    int pos = 0;
#pragma unroll
    for (int ee = 0; ee < NEXP; ee++) {
      unsigned long long m = __ballot(e == ee);
      if (m) {  // wave-uniform
        int leader = __ffsll((long long)m) - 1;
        int base = 0;
        if (lane == leader) base = atomicAdd(&scur[ee], __popcll(m));
        base = __shfl(base, leader);
        if (e == ee) pos = base + __popcll(m & ltmask);
      }
    }
    slot_token[pos] = i >> 1;
    slot_w[pos] = topk_w[i];
  }
}

// ---- transpose + convert: in fp32 [R][C] -> out bf16 [C][R] ----------------
__global__ __launch_bounds__(256) void transpose_k(const float* __restrict__ in,
                                                   __bf16* __restrict__ out,
                                                   int R, int C) {
  __shared__ float tile[64][132];  // [c][r], stride 132 breaks pow2 conflicts
  size_t mo = (size_t)blockIdx.z * (size_t)R * C;
  int c0 = blockIdx.x * 64, r0 = blockIdx.y * 128;
  int t = threadIdx.x;  // 256 threads
#pragma unroll
  for (int i = 0; i < 8; i++) {
    int idx = t + i * 256;    // 0..2047
    int r = idx >> 4;         // 0..127
    int c4 = (idx & 15) * 4;  // 0..60
    float4 v = *(const float4*)(in + mo + (size_t)(r0 + r) * C + c0 + c4);
    tile[c4 + 0][r] = v.x;
    tile[c4 + 1][r] = v.y;
    tile[c4 + 2][r] = v.z;
    tile[c4 + 3][r] = v.w;
  }
  __syncthreads();
#pragma unroll
  for (int i = 0; i < 4; i++) {
    int jdx = t + i * 256;    // 0..1023
    int c = jdx >> 4;         // 0..63
    int rr = (jdx & 15) * 8;  // 0..120
    bf16x8 o;
#pragma unroll
    for (int j = 0; j < 8; j++) o[j] = (__bf16)tile[c][rr + j];
    *(bf16x8*)(out + mo + (size_t)(c0 + c) * R + r0 + rr) = o;
  }
}

// ---------------- G1: gathered A @ [wgT|wuT], fused swiglu+weight -> inter ---
// 512 threads, tile 256(M)x128(N), BK=64, DOUBLE-BUFFERED LDS (128 KB).
// Prefetch of K-tile t+1 issued BEFORE computing tile t (T3 minimum 2-phase).
// Per-buffer strides: A 32768 B, Bg/Bu 16384 B  (round-4 bug: used total
// array size as stride -> buffer 1 overwrote the neighbor arrays -> NaN).
__global__ __launch_bounds__(512, 2) void g1_k(
    const __bf16* __restrict__ xb, const __bf16* __restrict__ wgT,
    const __bf16* __restrict__ wuT, __bf16* __restrict__ inter,
    const int* __restrict__ slot_token, const float* __restrict__ slot_w,
    const int* __restrict__ counts, const int* __restrict__ offs) {
  int e = blockIdx.z;
  int cnt = counts[e];
  int m0 = blockIdx.y * 256;
  if (m0 >= cnt) return;
  int n0 = blockIdx.x * 128;
  int base = offs[e];

  __shared__ __align__(16) __bf16 As[2][256][64];   // 2 x 32 KB
  __shared__ __align__(16) __bf16 Bgs[2][128][64];  // 2 x 16 KB
  __shared__ __align__(16) __bf16 Bus[2][128][64];  // 2 x 16 KB

  int t = threadIdx.x;
  int lane = t & 63, wv = t >> 6;            // wv 0..7
  int rbase = t >> 3;                        // staging row 0..63
  int kcol = (((t & 7) ^ (rbase & 7)) * 8);  // XOR-swizzled source col

  const __bf16* arow[4];
#pragma unroll
  for (int i = 0; i < 4; i++) {
    int gm = m0 + rbase + i * 64;
    int slot = base + min(gm, cnt - 1);
    arow[i] = xb + (size_t)slot_token[slot] * HID + kcol;
  }
  const __bf16* bg = wgT + ((size_t)e * INTER_D + n0 + rbase) * HID + kcol;
  const __bf16* bu = wuT + ((size_t)e * INTER_D + n0 + rbase) * HID + kcol;

  // wave-uniform LDS staging bases (hardware adds lane*16)
  char* aB = (char*)As + wv * 1024;
  char* gB = (char*)Bgs + wv * 1024;
  char* uB = (char*)Bus + wv * 1024;

  f32x16 accg[4], accu[4];
#pragma unroll
  for (int i = 0; i < 4; i++) {
    accg[i] = (f32x16)(0.f);
    accu[i] = (f32x16)(0.f);
  }

  int wm = (wv >> 1) * 64, wn = (wv & 1) * 64;  // 4M x 2N wave grid
  int ln31 = lane & 31, half = lane >> 5;
  int sw = ln31 & 7;

#define G1_STAGE(buf, k0)                                                      \
  {                                                                            \
    char* la = aB + (buf)*32768; /* per-buffer stride of As */                 \
    char* lg = gB + (buf)*16384; /* per-buffer stride of Bgs */                \
    char* lu = uB + (buf)*16384; /* per-buffer stride of Bus */                \
    _Pragma("unroll") for (int i = 0; i < 4; i++)                              \
        async16(arow[i] + (k0), la + i * 8192);                                \
    _Pragma("unroll") for (int i = 0; i < 2; i++) {                            \
      async16(bg + (size_t)(i * 64) * HID + (k0), lg + i * 8192);              \
      async16(bu + (size_t)(i * 64) * HID + (k0), lu + i * 8192);              \
    }                                                                          \
  }

  G1_STAGE(0, 0);
  asm volatile("s_waitcnt vmcnt(0)");
  __syncthreads();

  for (int kt = 0; kt < HID / 64; kt++) {
    int cur = kt & 1;
    if (kt + 1 < HID / 64) G1_STAGE(cur ^ 1, (kt + 1) * 64);
    __builtin_amdgcn_sched_barrier(0);  // keep prefetch above the MFMA cluster
#pragma unroll
    for (int kk = 0; kk < 4; kk++) {
      int col0 = ((kk * 2 + half) ^ sw) * 8;  // de-swizzled read column
      bf16x8 a[2], g[2], u[2];
#pragma unroll
      for (int i = 0; i < 2; i++) {
        a[i] = *(const bf16x8*)&As[cur][wm + i * 32 + ln31][col0];
        g[i] = *(const bf16x8*)&Bgs[cur][wn + i * 32 + ln31][col0];
        u[i] = *(const bf16x8*)&Bus[cur][wn + i * 32 + ln31][col0];
      }
#pragma unroll
      for (int i = 0; i < 2; i++)
#pragma unroll
        for (int j = 0; j < 2; j++) {
          accg[i * 2 + j] = MFMA32(a[i], g[j], accg[i * 2 + j]);
          accu[i * 2 + j] = MFMA32(a[i], u[j], accu[i * 2 + j]);
        }
    }
    asm volatile("s_waitcnt vmcnt(0)");
    __syncthreads();
  }
#undef G1_STAGE

#pragma unroll
  for (int i = 0; i < 2; i++) {
#pragma unroll
    for (int r = 0; r < 16; r++) {
      int m_in = wm + i * 32 + (r & 3) + 8 * (r >> 2) + 4 * half;
      int gm = m0 + m_in;
      if (gm < cnt) {
        int slot = base + gm;
        float w = slot_w[slot];
        __bf16* orow = inter + (size_t)slot * INTER_D + n0 + wn + ln31;
#pragma unroll
        for (int j = 0; j < 2; j++) {
          float gg = accg[i * 2 + j][r];
          float uu = accu[i * 2 + j][r];
          float sg = 1.f / (1.f + __expf(-gg));
          orow[j * 32] = (__bf16)(w * gg * sg * uu);
        }
      }
    }
  }
}

// ---------------- G2: inter @ wdT, atomic combine into out -------------------
// 256 threads, 128x128 tile, BK=64, double-buffered (64 KB LDS, 2 blocks/CU).
__global__ __launch_bounds__(256, 2) void g2_k(
    const __bf16* __restrict__ inter, const __bf16* __restrict__ wdT,
    float* __restrict__ out, const int* __restrict__ slot_token,
    const int* __restrict__ counts, const int* __restrict__ offs) {
  int e = blockIdx.z;
  int cnt = counts[e];
  int m0 = blockIdx.y * 128;
  if (m0 >= cnt) return;
  int n0 = blockIdx.x * 128;
  int base = offs[e];

  __shared__ __align__(16) __bf16 As[2][128][64];  // 2 x 16 KB
  __shared__ __align__(16) __bf16 Bs[2][128][64];  // 2 x 16 KB

  int t = threadIdx.x;
  int lane = t & 63, wv = t >> 6;
  int rbase = t >> 3;  // 0..31
  int kcol = (((t & 7) ^ (rbase & 7)) * 8);

  const __bf16* arow[4];
#pragma unroll
  for (int i = 0; i < 4; i++) {
    int gm = m0 + rbase + i * 32;
    arow[i] = inter + (size_t)(base + min(gm, cnt - 1)) * INTER_D + kcol;
  }
  const __bf16* brow = wdT + ((size_t)e * HID + n0 + rbase) * INTER_D + kcol;

  char* aB = (char*)As + wv * 1024;
  char* bB = (char*)Bs + wv * 1024;

  f32x16 acc[4];
#pragma unroll
  for (int i = 0; i < 4; i++) acc[i] = (f32x16)(0.f);

  int wm = (wv & 1) * 64, wn = (wv >> 1) * 64;
  int ln31 = lane & 31, half = lane >> 5;
  int sw = ln31 & 7;

#define G2_STAGE(buf, k0)                                                      \
  {                                                                            \
    char* la = aB + (buf)*16384; /* per-buffer stride of As */                 \
    char* lb = bB + (buf)*16384; /* per-buffer stride of Bs */                 \
    _Pragma("unroll") for (int i = 0; i < 4; i++) {                            \
      async16(arow[i] + (k0), la + i * 4096);                                  \
      async16(brow + (size_t)(i * 32) * INTER_D + (k0), lb + i * 4096);        \
    }                                                                          \
  }

  G2_STAGE(0, 0);
  asm volatile("s_waitcnt vmcnt(0)");
  __syncthreads();

  for (int kt = 0; kt < INTER_D / 64; kt++) {
    int cur = kt & 1;
    if (kt + 1 < INTER_D / 64) G2_STAGE(cur ^ 1, (kt + 1) * 64);
    __builtin_amdgcn_sched_barrier(0);
#pragma unroll
    for (int kk = 0; kk < 4; kk++) {
      int col0 = ((kk * 2 + half) ^ sw) * 8;
      bf16x8 a[2], b[2];
#pragma unroll
      for (int i = 0; i < 2; i++) {
        a[i] = *(const bf16x8*)&As[cur][wm + i * 32 + ln31][col0];
        b[i] = *(const bf16x8*)&Bs[cur][wn + i * 32 + ln31][col0];
      }
#pragma unroll
      for (int i = 0; i < 2; i++)
#pragma unroll
        for (int j = 0; j < 2; j++) acc[i * 2 + j] = MFMA32(a[i], b[j], acc[i * 2 + j]);
    }
    asm volatile("s_waitcnt vmcnt(0)");
    __syncthreads();
  }
#undef G2_STAGE

#pragma unroll
  for (int i = 0; i < 2; i++) {
#pragma unroll
    for (int r = 0; r < 16; r++) {
      int m_in = wm + i * 32 + (r & 3) + 8 * (r >> 2) + 4 * half;
      int gm = m0 + m_in;
      if (gm < cnt) {
        int tok = slot_token[base + gm];
        float* orow = out + (size_t)tok * HID + n0 + wn + ln31;
#pragma unroll
        for (int j = 0; j < 2; j++) atomicAdd(&orow[j * 32], acc[i * 2 + j][r]);
      }
    }
  }
}

extern "C" void kernel_launch(void* const* d_in, const int* in_sizes, int n_in,
                              void* d_out, int out_size, void* d_ws, size_t ws_size,
                              hipStream_t stream) {
  const float* x = (const float*)d_in[0];
  const float* rw = (const float*)d_in[1];
  const float* wg = (const float*)d_in[2];
  const float* wu = (const float*)d_in[3];
  const float* wd = (const float*)d_in[4];
  float* out = (float*)d_out;
  char* ws = (char*)d_ws;

  if (ws_size < WS_NEED) return;

  __bf16* xb = (__bf16*)(ws + XB_OFF);
  __bf16* wgT = (__bf16*)(ws + WGT_OFF);
  __bf16* wuT = (__bf16*)(ws + WUT_OFF);
  __bf16* wdT = (__bf16*)(ws + WDT_OFF);
  __bf16* inter = (__bf16*)(ws + INTER_OFF);
  int* slot_token = (int*)(ws + ST_OFF);
  float* slot_w = (float*)(ws + SW_OFF);
  int* topk_idx = (int*)(ws + TI_OFF);
  float* topk_w = (float*)(ws + TW_OFF);
  int* counts = (int*)(ws + CTRL_OFF);
  int* offs = (int*)(ws + CTRL_OFF + 64);

  hipMemsetAsync(d_out, 0, (size_t)T_TOK * HID * sizeof(float), stream);
  hipMemsetAsync(ws + CTRL_OFF, 0, 256, stream);

  router_k<<<T_TOK, 64, 0, stream>>>(x, rw, xb, topk_idx, topk_w, counts);
  scatter_k<<<1, 256, 0, stream>>>(topk_idx, topk_w, counts, offs, slot_token, slot_w);
  // wg, wu: [H][I] -> [I][H];  wd: [I][H] -> [H][I]
  transpose_k<<<dim3(INTER_D / 64, HID / 128, NEXP), 256, 0, stream>>>(wg, wgT, HID, INTER_D);
  transpose_k<<<dim3(INTER_D / 64, HID / 128, NEXP), 256, 0, stream>>>(wu, wuT, HID, INTER_D);
  transpose_k<<<dim3(HID / 64, INTER_D / 128, NEXP), 256, 0, stream>>>(wd, wdT, INTER_D, HID);
  g1_k<<<dim3(INTER_D / 128, T_TOK / 256, NEXP), 512, 0, stream>>>(
      xb, wgT, wuT, inter, slot_token, slot_w, counts, offs);
  g2_k<<<dim3(HID / 128, T_TOK / 128, NEXP), 256, 0, stream>>>(
      inter, wdT, out, slot_token, counts, offs);
}